// Round 1
// baseline (401.576 us; speedup 1.0000x reference)
//
#include <hip/hip_runtime.h>
#include <hip/hip_bf16.h>

// Problem constants (static per the reference)
#define LQ     12240
#define CDIM   256
#define HEADS  8
#define LEVELS 4
#define FRAMES 4
#define POINTS 4
#define DHEAD  32
#define OFFDIM 1024   // HEADS*LEVELS*FRAMES*POINTS*2
#define ATTND  512    // HEADS*LEVELS*FRAMES*POINTS

// ---------------------------------------------------------------------------
// Generic f32 GEMM with bias: C[M,N] = A[M,K] @ B[K,N] + bias[N]
// Tile 64x64, BK=16, 256 threads, each thread 4x4 outputs.
// ---------------------------------------------------------------------------
__global__ __launch_bounds__(256) void gemm_bias_kernel(
    const float* __restrict__ A, const float* __restrict__ B,
    const float* __restrict__ bias, float* __restrict__ C,
    int M, int N, int K) {
  __shared__ float As[16][64];  // [k][m] (transposed store)
  __shared__ float Bs[16][64];  // [k][n]

  const int tid = threadIdx.x;
  const int bm = blockIdx.y * 64;
  const int bn = blockIdx.x * 64;
  const int tx = tid & 15;      // 16 cols of threads
  const int ty = tid >> 4;      // 16 rows of threads

  // load mapping
  const int arow  = tid & 63;         // 0..63
  const int acol4 = (tid >> 6) * 4;   // 0,4,8,12
  const int brow  = tid >> 4;         // 0..15
  const int bcol4 = (tid & 15) * 4;   // 0..60

  float acc[4][4] = {};

  for (int k0 = 0; k0 < K; k0 += 16) {
    const int gr = bm + arow;
    float4 av;
    if (gr < M) {
      av = *reinterpret_cast<const float4*>(&A[(size_t)gr * K + k0 + acol4]);
    } else {
      av = make_float4(0.f, 0.f, 0.f, 0.f);
    }
    As[acol4 + 0][arow] = av.x;
    As[acol4 + 1][arow] = av.y;
    As[acol4 + 2][arow] = av.z;
    As[acol4 + 3][arow] = av.w;

    float4 bv = *reinterpret_cast<const float4*>(&B[(size_t)(k0 + brow) * N + bn + bcol4]);
    Bs[brow][bcol4 + 0] = bv.x;
    Bs[brow][bcol4 + 1] = bv.y;
    Bs[brow][bcol4 + 2] = bv.z;
    Bs[brow][bcol4 + 3] = bv.w;

    __syncthreads();

#pragma unroll
    for (int k = 0; k < 16; ++k) {
      float ar[4], br[4];
#pragma unroll
      for (int i = 0; i < 4; ++i) ar[i] = As[k][ty * 4 + i];
#pragma unroll
      for (int j = 0; j < 4; ++j) br[j] = Bs[k][tx * 4 + j];
#pragma unroll
      for (int i = 0; i < 4; ++i)
#pragma unroll
        for (int j = 0; j < 4; ++j)
          acc[i][j] = fmaf(ar[i], br[j], acc[i][j]);
    }
    __syncthreads();
  }

#pragma unroll
  for (int i = 0; i < 4; ++i) {
    const int gr = bm + ty * 4 + i;
    if (gr >= M) continue;
#pragma unroll
    for (int j = 0; j < 4; ++j) {
      const int gc = bn + tx * 4 + j;
      C[(size_t)gr * N + gc] = acc[i][j] + bias[gc];
    }
  }
}

// ---------------------------------------------------------------------------
// Fused softmax + location + deformable bilinear sampling.
// One block (256 threads) per query. Thread = (head = tid>>5, dim = tid&31).
// "Grid" per level is (H*W rows) x (T=4 cols): x spans frames, y spans pixels.
// ---------------------------------------------------------------------------
__global__ __launch_bounds__(256) void sample_kernel(
    const float* __restrict__ value,      // (LQ, 8, 32) flattened (LQ, 256)
    const float* __restrict__ logits,     // (LQ, 512)
    const float* __restrict__ off,        // (LQ, 1024)
    const float* __restrict__ tempoff,    // (LQ, 4, 4, 2)
    const float* __restrict__ refpts,     // (LQ, 4, 2)
    float* __restrict__ msout) {          // (LQ, 256)
  const int q = blockIdx.x;
  const int tid = threadIdx.x;

  __shared__ float sw[512];   // attention weights (softmaxed)
  __shared__ float sx[512];   // pixel x coords (frame axis)
  __shared__ float sy[512];   // pixel y coords (flattened-pixel axis)
  __shared__ float smax[8], sinv[8];

  // load logits
  for (int i = tid; i < 512; i += 256) sw[i] = logits[(size_t)q * 512 + i];
  __syncthreads();

  // per-head softmax (8 serial threads; 64 elems each)
  if (tid < 8) {
    float m = -1e30f;
    for (int j = 0; j < 64; ++j) m = fmaxf(m, sw[tid * 64 + j]);
    float s = 0.f;
    for (int j = 0; j < 64; ++j) s += __expf(sw[tid * 64 + j] - m);
    smax[tid] = m;
    sinv[tid] = 1.0f / s;
  }
  __syncthreads();
  for (int i = tid; i < 512; i += 256) {
    const int h = i >> 6;
    sw[i] = __expf(sw[i] - smax[h]) * sinv[h];
  }

  // sampling locations: i = h*64 + l*16 + f*4 + p
  const float HWF[4] = {2304.f, 576.f, 144.f, 36.f};
  for (int i = tid; i < 512; i += 256) {
    const int l = (i >> 4) & 3;
    const int f = (i >> 2) & 3;
    const float ox = off[(size_t)q * 1024 + i * 2 + 0];
    const float oy = off[(size_t)q * 1024 + i * 2 + 1];
    const float hw = HWF[l];
    const float lx = tempoff[(size_t)q * 32 + (l * 4 + f) * 2 + 0] + ox * 0.25f
                   + refpts[(size_t)q * 8 + l * 2 + 0];
    const float ly = tempoff[(size_t)q * 32 + (l * 4 + f) * 2 + 1] + oy / hw
                   + refpts[(size_t)q * 8 + l * 2 + 1];
    sx[i] = lx * 4.0f - 0.5f;   // wl = T = 4
    sy[i] = ly * hw - 0.5f;     // hl = H*W
  }
  __syncthreads();

  const int h = tid >> 5;
  const int d = tid & 31;
  const int S0[4] = {0, 9216, 11520, 12096};
  const int HWI[4] = {2304, 576, 144, 36};

  float acc = 0.f;
#pragma unroll
  for (int l = 0; l < 4; ++l) {
    const float* vbase = value + (size_t)S0[l] * 256 + h * 32 + d;
    const int hl = HWI[l];
#pragma unroll 4
    for (int fp = 0; fp < 16; ++fp) {
      const int i = h * 64 + l * 16 + fp;
      const float x = sx[i], y = sy[i], w = sw[i];
      const float x0f = floorf(x), y0f = floorf(y);
      const float fx = x - x0f, fy = y - y0f;
      const int x0 = (int)x0f, y0 = (int)y0f;

      const bool xv0 = (x0 >= 0) && (x0 < 4);
      const bool xv1 = (x0 + 1 >= 0) && (x0 + 1 < 4);
      const bool yv0 = (y0 >= 0) && (y0 < hl);
      const bool yv1 = (y0 + 1 >= 0) && (y0 + 1 < hl);
      const int xc0 = min(max(x0, 0), 3);
      const int xc1 = min(max(x0 + 1, 0), 3);
      const int yc0 = min(max(y0, 0), hl - 1);
      const int yc1 = min(max(y0 + 1, 0), hl - 1);

      const float v00 = vbase[(size_t)(yc0 * 4 + xc0) * 256];
      const float v01 = vbase[(size_t)(yc0 * 4 + xc1) * 256];
      const float v10 = vbase[(size_t)(yc1 * 4 + xc0) * 256];
      const float v11 = vbase[(size_t)(yc1 * 4 + xc1) * 256];

      const float w00 = (xv0 && yv0) ? (1.f - fx) * (1.f - fy) : 0.f;
      const float w01 = (xv1 && yv0) ? fx * (1.f - fy) : 0.f;
      const float w10 = (xv0 && yv1) ? (1.f - fx) * fy : 0.f;
      const float w11 = (xv1 && yv1) ? fx * fy : 0.f;

      acc += w * (v00 * w00 + v01 * w01 + v10 * w10 + v11 * w11);
    }
  }
  msout[(size_t)q * 256 + tid] = acc;
}

// ---------------------------------------------------------------------------
extern "C" void kernel_launch(void* const* d_in, const int* in_sizes, int n_in,
                              void* d_out, int out_size, void* d_ws, size_t ws_size,
                              hipStream_t stream) {
  const float* query   = (const float*)d_in[0];
  const float* refpts  = (const float*)d_in[1];
  const float* tempoff = (const float*)d_in[2];
  const float* inflat  = (const float*)d_in[3];
  // d_in[4] = shapes, d_in[5] = starts -> static, hard-coded
  const float* W_off  = (const float*)d_in[6];
  const float* b_off  = (const float*)d_in[7];
  const float* W_attn = (const float*)d_in[8];
  const float* b_attn = (const float*)d_in[9];
  const float* W_val  = (const float*)d_in[10];
  const float* b_val  = (const float*)d_in[11];
  const float* W_out  = (const float*)d_in[12];
  const float* b_out  = (const float*)d_in[13];

  float* ws = (float*)d_ws;
  float* v_val  = ws;                          // LQ*256
  float* v_attn = v_val + (size_t)LQ * 256;    // LQ*512
  float* v_off  = v_attn + (size_t)LQ * 512;   // LQ*1024
  float* v_ms   = v_off + (size_t)LQ * 1024;   // LQ*256
  float* outp = (float*)d_out;

  dim3 block(256);
  const int gm = (LQ + 63) / 64;  // 192

  gemm_bias_kernel<<<dim3(256 / 64, gm), block, 0, stream>>>(
      inflat, W_val, b_val, v_val, LQ, 256, 256);
  gemm_bias_kernel<<<dim3(512 / 64, gm), block, 0, stream>>>(
      query, W_attn, b_attn, v_attn, LQ, 512, 256);
  gemm_bias_kernel<<<dim3(1024 / 64, gm), block, 0, stream>>>(
      query, W_off, b_off, v_off, LQ, 1024, 256);
  sample_kernel<<<dim3(LQ), block, 0, stream>>>(
      v_val, v_attn, v_off, tempoff, refpts, v_ms);
  gemm_bias_kernel<<<dim3(256 / 64, gm), block, 0, stream>>>(
      v_ms, W_out, b_out, outp, LQ, 256, 256);
}

// Round 2
// 372.512 us; speedup vs baseline: 1.0780x; 1.0780x over previous
//
#include <hip/hip_runtime.h>
#include <hip/hip_bf16.h>

// Problem constants (static per the reference)
#define LQ     12240
#define CDIM   256
#define HEADS  8
#define LEVELS 4
#define FRAMES 4
#define POINTS 4
#define DHEAD  32

// ---------------------------------------------------------------------------
// Generic f32 GEMM with bias: C[M,N] = A[M,K] @ B[K,N] + bias[N]
// Tile 64x64, BK=16, 256 threads, each thread 4x4 outputs.
// ---------------------------------------------------------------------------
__global__ __launch_bounds__(256) void gemm_bias_kernel(
    const float* __restrict__ A, const float* __restrict__ B,
    const float* __restrict__ bias, float* __restrict__ C,
    int M, int N, int K) {
  __shared__ float As[16][64];  // [k][m] (transposed store)
  __shared__ float Bs[16][64];  // [k][n]

  const int tid = threadIdx.x;
  const int bm = blockIdx.y * 64;
  const int bn = blockIdx.x * 64;
  const int tx = tid & 15;
  const int ty = tid >> 4;

  const int arow  = tid & 63;
  const int acol4 = (tid >> 6) * 4;
  const int brow  = tid >> 4;
  const int bcol4 = (tid & 15) * 4;

  float acc[4][4] = {};

  for (int k0 = 0; k0 < K; k0 += 16) {
    const int gr = bm + arow;
    float4 av;
    if (gr < M) {
      av = *reinterpret_cast<const float4*>(&A[(size_t)gr * K + k0 + acol4]);
    } else {
      av = make_float4(0.f, 0.f, 0.f, 0.f);
    }
    As[acol4 + 0][arow] = av.x;
    As[acol4 + 1][arow] = av.y;
    As[acol4 + 2][arow] = av.z;
    As[acol4 + 3][arow] = av.w;

    float4 bv = *reinterpret_cast<const float4*>(&B[(size_t)(k0 + brow) * N + bn + bcol4]);
    Bs[brow][bcol4 + 0] = bv.x;
    Bs[brow][bcol4 + 1] = bv.y;
    Bs[brow][bcol4 + 2] = bv.z;
    Bs[brow][bcol4 + 3] = bv.w;

    __syncthreads();

#pragma unroll
    for (int k = 0; k < 16; ++k) {
      float ar[4], br[4];
#pragma unroll
      for (int i = 0; i < 4; ++i) ar[i] = As[k][ty * 4 + i];
#pragma unroll
      for (int j = 0; j < 4; ++j) br[j] = Bs[k][tx * 4 + j];
#pragma unroll
      for (int i = 0; i < 4; ++i)
#pragma unroll
        for (int j = 0; j < 4; ++j)
          acc[i][j] = fmaf(ar[i], br[j], acc[i][j]);
    }
    __syncthreads();
  }

#pragma unroll
  for (int i = 0; i < 4; ++i) {
    const int gr = bm + ty * 4 + i;
    if (gr >= M) continue;
#pragma unroll
    for (int j = 0; j < 4; ++j) {
      const int gc = bn + tx * 4 + j;
      C[(size_t)gr * N + gc] = acc[i][j] + bias[gc];
    }
  }
}

// ---------------------------------------------------------------------------
// Fused softmax + location + deformable bilinear sampling, 2 queries / block.
// Phase 1: per-sample softmax weight, 4 combined corner weights, 4 corner
//          element offsets -> LDS (computed once, not per dim-lane).
// Phase 2: thread = (query, head, lane16); pure gather + FMA with float2
//          loads; weights/offsets broadcast from LDS via b128 reads.
// ---------------------------------------------------------------------------
__global__ __launch_bounds__(256) void sample_kernel(
    const float* __restrict__ value,      // (LQ, 256) = (LQ, 8, 32)
    const float* __restrict__ logits,     // (LQ, 512)
    const float* __restrict__ off,        // (LQ, 1024)
    const float* __restrict__ tempoff,    // (LQ, 4, 4, 2)
    const float* __restrict__ refpts,     // (LQ, 4, 2)
    float* __restrict__ msout) {          // (LQ, 256)
  const int q0 = blockIdx.x * 2;
  const int tid = threadIdx.x;

  __shared__ float  slog[1024];   // logits, 2 queries
  __shared__ float4 scw[1024];    // combined corner weights (attn * bilinear)
  __shared__ int4   soff[1024];   // corner element offsets into value
  __shared__ float  sm_m[16], sm_si[16];

  // ---- load logits (2 queries x 512) ----
#pragma unroll
  for (int k = 0; k < 4; ++k) {
    const int s = tid + k * 256;
    slog[s] = logits[(size_t)(q0 + (s >> 9)) * 512 + (s & 511)];
  }
  __syncthreads();

  // ---- per-(query,head) softmax stats: 16 groups x 16 threads ----
  {
    const int g = tid >> 4;    // 0..15, only first 256 threads -> all groups
    const int j = tid & 15;
    const float* e = &slog[g * 64];
    float m = fmaxf(fmaxf(e[j], e[j + 16]), fmaxf(e[j + 32], e[j + 48]));
#pragma unroll
    for (int mask = 8; mask >= 1; mask >>= 1) m = fmaxf(m, __shfl_xor(m, mask));
    float s = __expf(e[j] - m) + __expf(e[j + 16] - m) +
              __expf(e[j + 32] - m) + __expf(e[j + 48] - m);
#pragma unroll
    for (int mask = 8; mask >= 1; mask >>= 1) s += __shfl_xor(s, mask);
    if (j == 0) { sm_m[g] = m; sm_si[g] = 1.0f / s; }
  }
  __syncthreads();

  // ---- per-sample weights + corner offsets ----
  const float HWF[4] = {2304.f, 576.f, 144.f, 36.f};
  const float RHW[4] = {1.f / 2304.f, 1.f / 576.f, 1.f / 144.f, 1.f / 36.f};
  const int   S0[4]  = {0, 9216, 11520, 12096};
  const int   HWI[4] = {2304, 576, 144, 36};

#pragma unroll
  for (int k = 0; k < 4; ++k) {
    const int s  = tid + k * 256;
    const int qi = s >> 9;
    const int i  = s & 511;
    const int l  = (i >> 4) & 3;
    const int f  = (i >> 2) & 3;
    const size_t q = (size_t)(q0 + qi);

    const float w = __expf(slog[s] - sm_m[s >> 6]) * sm_si[s >> 6];

    const float2 o  = *reinterpret_cast<const float2*>(&off[q * 1024 + i * 2]);
    const float2 to = *reinterpret_cast<const float2*>(&tempoff[q * 32 + (l * 4 + f) * 2]);
    const float2 rp = *reinterpret_cast<const float2*>(&refpts[q * 8 + l * 2]);

    const float hw = HWF[l];
    const float lx = to.x + o.x * 0.25f + rp.x;
    const float ly = to.y + o.y * RHW[l] + rp.y;
    const float x = lx * 4.0f - 0.5f;
    const float y = ly * hw - 0.5f;

    const float x0f = floorf(x), y0f = floorf(y);
    const float fx = x - x0f, fy = y - y0f;
    const int x0 = (int)x0f, y0 = (int)y0f;
    const int hl = HWI[l];

    const bool xv0 = (x0 >= 0) && (x0 < 4);
    const bool xv1 = (x0 >= -1) && (x0 < 3);
    const bool yv0 = (y0 >= 0) && (y0 < hl);
    const bool yv1 = (y0 >= -1) && (y0 < hl - 1);
    const int xc0 = min(max(x0, 0), 3);
    const int xc1 = min(max(x0 + 1, 0), 3);
    const int yc0 = min(max(y0, 0), hl - 1);
    const int yc1 = min(max(y0 + 1, 0), hl - 1);

    scw[s] = make_float4((xv0 && yv0) ? w * (1.f - fx) * (1.f - fy) : 0.f,
                         (xv1 && yv0) ? w * fx * (1.f - fy) : 0.f,
                         (xv0 && yv1) ? w * (1.f - fx) * fy : 0.f,
                         (xv1 && yv1) ? w * fx * fy : 0.f);
    const int base = S0[l];
    soff[s] = make_int4((base + yc0 * 4 + xc0) * 256,
                        (base + yc0 * 4 + xc1) * 256,
                        (base + yc1 * 4 + xc0) * 256,
                        (base + yc1 * 4 + xc1) * 256);
  }
  __syncthreads();

  // ---- phase 2: gather + FMA ----
  const int qi = tid >> 7;          // 0..1
  const int h  = (tid >> 4) & 7;    // 0..7
  const int d  = (tid & 15) * 2;    // 0..30 (float2)

  const float* __restrict__ vb = value + h * 32 + d;
  float2 acc = make_float2(0.f, 0.f);
  const int sbase = qi * 512 + h * 64;

#pragma unroll 4
  for (int k = 0; k < 64; ++k) {
    const float4 cw = scw[sbase + k];
    const int4   eo = soff[sbase + k];
    const float2 v0 = *reinterpret_cast<const float2*>(vb + eo.x);
    const float2 v1 = *reinterpret_cast<const float2*>(vb + eo.y);
    const float2 v2 = *reinterpret_cast<const float2*>(vb + eo.z);
    const float2 v3 = *reinterpret_cast<const float2*>(vb + eo.w);
    acc.x = fmaf(cw.x, v0.x, acc.x);
    acc.y = fmaf(cw.x, v0.y, acc.y);
    acc.x = fmaf(cw.y, v1.x, acc.x);
    acc.y = fmaf(cw.y, v1.y, acc.y);
    acc.x = fmaf(cw.z, v2.x, acc.x);
    acc.y = fmaf(cw.z, v2.y, acc.y);
    acc.x = fmaf(cw.w, v3.x, acc.x);
    acc.y = fmaf(cw.w, v3.y, acc.y);
  }
  *reinterpret_cast<float2*>(&msout[(size_t)(q0 + qi) * 256 + h * 32 + d]) = acc;
}

// ---------------------------------------------------------------------------
extern "C" void kernel_launch(void* const* d_in, const int* in_sizes, int n_in,
                              void* d_out, int out_size, void* d_ws, size_t ws_size,
                              hipStream_t stream) {
  const float* query   = (const float*)d_in[0];
  const float* refpts  = (const float*)d_in[1];
  const float* tempoff = (const float*)d_in[2];
  const float* inflat  = (const float*)d_in[3];
  const float* W_off  = (const float*)d_in[6];
  const float* b_off  = (const float*)d_in[7];
  const float* W_attn = (const float*)d_in[8];
  const float* b_attn = (const float*)d_in[9];
  const float* W_val  = (const float*)d_in[10];
  const float* b_val  = (const float*)d_in[11];
  const float* W_out  = (const float*)d_in[12];
  const float* b_out  = (const float*)d_in[13];

  float* ws = (float*)d_ws;
  float* v_val  = ws;                          // LQ*256
  float* v_attn = v_val + (size_t)LQ * 256;    // LQ*512
  float* v_off  = v_attn + (size_t)LQ * 512;   // LQ*1024
  float* v_ms   = v_off + (size_t)LQ * 1024;   // LQ*256
  float* outp = (float*)d_out;

  dim3 block(256);
  const int gm = (LQ + 63) / 64;  // 192

  gemm_bias_kernel<<<dim3(256 / 64, gm), block, 0, stream>>>(
      inflat, W_val, b_val, v_val, LQ, 256, 256);
  gemm_bias_kernel<<<dim3(512 / 64, gm), block, 0, stream>>>(
      query, W_attn, b_attn, v_attn, LQ, 512, 256);
  gemm_bias_kernel<<<dim3(1024 / 64, gm), block, 0, stream>>>(
      query, W_off, b_off, v_off, LQ, 1024, 256);
  sample_kernel<<<dim3(LQ / 2), block, 0, stream>>>(
      v_val, v_attn, v_off, tempoff, refpts, v_ms);
  gemm_bias_kernel<<<dim3(256 / 64, gm), block, 0, stream>>>(
      v_ms, W_out, b_out, outp, LQ, 256, 256);
}

// Round 3
// 367.778 us; speedup vs baseline: 1.0919x; 1.0129x over previous
//
#include <hip/hip_runtime.h>
#include <hip/hip_bf16.h>
#include <hip/hip_fp16.h>

// Problem constants (static per the reference)
#define LQ     12240
#define CDIM   256
#define HEADS  8
#define LEVELS 4
#define FRAMES 4
#define POINTS 4
#define DHEAD  32

// ---------------------------------------------------------------------------
// Generic f32 GEMM with bias: C[M,N] = A[M,K] @ B[K,N] + bias[N]
// Tile 64x64, BK=16, 256 threads, each thread 4x4 outputs.
// ---------------------------------------------------------------------------
__global__ __launch_bounds__(256) void gemm_bias_kernel(
    const float* __restrict__ A, const float* __restrict__ B,
    const float* __restrict__ bias, float* __restrict__ C,
    int M, int N, int K) {
  __shared__ float As[16][64];  // [k][m] (transposed store)
  __shared__ float Bs[16][64];  // [k][n]

  const int tid = threadIdx.x;
  const int bm = blockIdx.y * 64;
  const int bn = blockIdx.x * 64;
  const int tx = tid & 15;
  const int ty = tid >> 4;

  const int arow  = tid & 63;
  const int acol4 = (tid >> 6) * 4;
  const int brow  = tid >> 4;
  const int bcol4 = (tid & 15) * 4;

  float acc[4][4] = {};

  for (int k0 = 0; k0 < K; k0 += 16) {
    const int gr = bm + arow;
    float4 av;
    if (gr < M) {
      av = *reinterpret_cast<const float4*>(&A[(size_t)gr * K + k0 + acol4]);
    } else {
      av = make_float4(0.f, 0.f, 0.f, 0.f);
    }
    As[acol4 + 0][arow] = av.x;
    As[acol4 + 1][arow] = av.y;
    As[acol4 + 2][arow] = av.z;
    As[acol4 + 3][arow] = av.w;

    float4 bv = *reinterpret_cast<const float4*>(&B[(size_t)(k0 + brow) * N + bn + bcol4]);
    Bs[brow][bcol4 + 0] = bv.x;
    Bs[brow][bcol4 + 1] = bv.y;
    Bs[brow][bcol4 + 2] = bv.z;
    Bs[brow][bcol4 + 3] = bv.w;

    __syncthreads();

#pragma unroll
    for (int k = 0; k < 16; ++k) {
      float ar[4], br[4];
#pragma unroll
      for (int i = 0; i < 4; ++i) ar[i] = As[k][ty * 4 + i];
#pragma unroll
      for (int j = 0; j < 4; ++j) br[j] = Bs[k][tx * 4 + j];
#pragma unroll
      for (int i = 0; i < 4; ++i)
#pragma unroll
        for (int j = 0; j < 4; ++j)
          acc[i][j] = fmaf(ar[i], br[j], acc[i][j]);
    }
    __syncthreads();
  }

#pragma unroll
  for (int i = 0; i < 4; ++i) {
    const int gr = bm + ty * 4 + i;
    if (gr >= M) continue;
#pragma unroll
    for (int j = 0; j < 4; ++j) {
      const int gc = bn + tx * 4 + j;
      C[(size_t)gr * N + gc] = acc[i][j] + bias[gc];
    }
  }
}

// ---------------------------------------------------------------------------
// Fused softmax + location + deformable bilinear sampling, 2 queries / block.
// Per-sample data packed to 16B in LDS (f16 weights + u16 row indices) and
// stored h-fastest with XOR swizzle so phase-2 reads are bank-conflict-free.
// LDS ~20.6KB -> 7 blocks/CU (occupancy ~87%).
// ---------------------------------------------------------------------------
__global__ __launch_bounds__(256) void sample_kernel(
    const float* __restrict__ value,      // (LQ, 256) = (LQ, 8, 32)
    const float* __restrict__ logits,     // (LQ, 512)
    const float* __restrict__ off,        // (LQ, 1024)
    const float* __restrict__ tempoff,    // (LQ, 4, 4, 2)
    const float* __restrict__ refpts,     // (LQ, 4, 2)
    float* __restrict__ msout) {          // (LQ, 256)
  const int q0 = blockIdx.x * 2;
  const int tid = threadIdx.x;

  __shared__ float slog[1024];   // logits, 2 queries
  __shared__ uint4 sdat[1024];   // packed: 4xf16 weights | 4xu16 row indices
  __shared__ float sm_m[16], sm_si[16];

  // ---- load logits (2 queries x 512) ----
#pragma unroll
  for (int k = 0; k < 4; ++k) {
    const int s = tid + k * 256;
    slog[s] = logits[(size_t)(q0 + (s >> 9)) * 512 + (s & 511)];
  }
  __syncthreads();

  // ---- per-(query,head) softmax stats: 16 groups x 16 threads ----
  {
    const int g = tid >> 4;
    const int j = tid & 15;
    const float* e = &slog[g * 64];
    float m = fmaxf(fmaxf(e[j], e[j + 16]), fmaxf(e[j + 32], e[j + 48]));
#pragma unroll
    for (int mask = 8; mask >= 1; mask >>= 1) m = fmaxf(m, __shfl_xor(m, mask));
    float s = __expf(e[j] - m) + __expf(e[j + 16] - m) +
              __expf(e[j + 32] - m) + __expf(e[j + 48] - m);
#pragma unroll
    for (int mask = 8; mask >= 1; mask >>= 1) s += __shfl_xor(s, mask);
    if (j == 0) { sm_m[g] = m; sm_si[g] = 1.0f / s; }
  }
  __syncthreads();

  // ---- per-sample combined weights + corner row indices -> packed LDS ----
  const float HWF[4] = {2304.f, 576.f, 144.f, 36.f};
  const float RHW[4] = {1.f / 2304.f, 1.f / 576.f, 1.f / 144.f, 1.f / 36.f};
  const int   S0[4]  = {0, 9216, 11520, 12096};
  const int   HWI[4] = {2304, 576, 144, 36};

#pragma unroll
  for (int k = 0; k < 4; ++k) {
    const int s  = tid + k * 256;
    const int qi = s >> 9;
    const int i  = s & 511;
    const int h  = i >> 6;
    const int r  = i & 63;        // l*16 + f*4 + p
    const int l  = r >> 4;
    const int f  = (r >> 2) & 3;
    const size_t q = (size_t)(q0 + qi);

    const float w = __expf(slog[s] - sm_m[s >> 6]) * sm_si[s >> 6];

    const float2 o  = *reinterpret_cast<const float2*>(&off[q * 1024 + i * 2]);
    const float2 to = *reinterpret_cast<const float2*>(&tempoff[q * 32 + (l * 4 + f) * 2]);
    const float2 rp = *reinterpret_cast<const float2*>(&refpts[q * 8 + l * 2]);

    const float hw = HWF[l];
    const float lx = to.x + o.x * 0.25f + rp.x;
    const float ly = to.y + o.y * RHW[l] + rp.y;
    const float x = lx * 4.0f - 0.5f;
    const float y = ly * hw - 0.5f;

    const float x0f = floorf(x), y0f = floorf(y);
    const float fx = x - x0f, fy = y - y0f;
    const int x0 = (int)x0f, y0 = (int)y0f;
    const int hl = HWI[l];

    const bool xv0 = (x0 >= 0) && (x0 < 4);
    const bool xv1 = (x0 >= -1) && (x0 < 3);
    const bool yv0 = (y0 >= 0) && (y0 < hl);
    const bool yv1 = (y0 >= -1) && (y0 < hl - 1);
    const int xc0 = min(max(x0, 0), 3);
    const int xc1 = min(max(x0 + 1, 0), 3);
    const int yc0 = min(max(y0, 0), hl - 1);
    const int yc1 = min(max(y0 + 1, 0), hl - 1);

    const float w00 = (xv0 && yv0) ? w * (1.f - fx) * (1.f - fy) : 0.f;
    const float w01 = (xv1 && yv0) ? w * fx * (1.f - fy) : 0.f;
    const float w10 = (xv0 && yv1) ? w * (1.f - fx) * fy : 0.f;
    const float w11 = (xv1 && yv1) ? w * fx * fy : 0.f;

    const int base = S0[l];
    const uint r00 = (uint)(base + yc0 * 4 + xc0);
    const uint r01 = (uint)(base + yc0 * 4 + xc1);
    const uint r10 = (uint)(base + yc1 * 4 + xc0);
    const uint r11 = (uint)(base + yc1 * 4 + xc1);

    const __half2 p01 = __floats2half2_rn(w00, w01);
    const __half2 p23 = __floats2half2_rn(w10, w11);
    uint4 pk;
    pk.x = *reinterpret_cast<const uint*>(&p01);
    pk.y = *reinterpret_cast<const uint*>(&p23);
    pk.z = r00 | (r01 << 16);
    pk.w = r10 | (r11 << 16);

    // h-fastest storage with XOR swizzle (bank-conflict-free reads + writes)
    sdat[(qi << 9) | (r << 3) | (h ^ (r & 7))] = pk;
  }
  __syncthreads();

  // ---- phase 2: gather + FMA ----
  const int qi = tid >> 7;          // 0..1
  const int h  = (tid >> 4) & 7;    // 0..7
  const int d  = (tid & 15) * 2;    // 0..30 (float2)

  const float* __restrict__ vb = value + h * 32 + d;
  float2 acc = make_float2(0.f, 0.f);
  const int sbase = qi << 9;

#pragma unroll 4
  for (int k = 0; k < 64; ++k) {
    const uint4 pk = sdat[sbase | (k << 3) | (h ^ (k & 7))];
    const float2 w01 = __half22float2(*reinterpret_cast<const __half2*>(&pk.x));
    const float2 w23 = __half22float2(*reinterpret_cast<const __half2*>(&pk.y));
    const float2 v0 = *reinterpret_cast<const float2*>(vb + ((pk.z & 0xffffu) << 8));
    const float2 v1 = *reinterpret_cast<const float2*>(vb + ((pk.z >> 16) << 8));
    const float2 v2 = *reinterpret_cast<const float2*>(vb + ((pk.w & 0xffffu) << 8));
    const float2 v3 = *reinterpret_cast<const float2*>(vb + ((pk.w >> 16) << 8));
    acc.x = fmaf(w01.x, v0.x, acc.x);
    acc.y = fmaf(w01.x, v0.y, acc.y);
    acc.x = fmaf(w01.y, v1.x, acc.x);
    acc.y = fmaf(w01.y, v1.y, acc.y);
    acc.x = fmaf(w23.x, v2.x, acc.x);
    acc.y = fmaf(w23.x, v2.y, acc.y);
    acc.x = fmaf(w23.y, v3.x, acc.x);
    acc.y = fmaf(w23.y, v3.y, acc.y);
  }
  *reinterpret_cast<float2*>(&msout[(size_t)(q0 + qi) * 256 + h * 32 + d]) = acc;
}

// ---------------------------------------------------------------------------
extern "C" void kernel_launch(void* const* d_in, const int* in_sizes, int n_in,
                              void* d_out, int out_size, void* d_ws, size_t ws_size,
                              hipStream_t stream) {
  const float* query   = (const float*)d_in[0];
  const float* refpts  = (const float*)d_in[1];
  const float* tempoff = (const float*)d_in[2];
  const float* inflat  = (const float*)d_in[3];
  const float* W_off  = (const float*)d_in[6];
  const float* b_off  = (const float*)d_in[7];
  const float* W_attn = (const float*)d_in[8];
  const float* b_attn = (const float*)d_in[9];
  const float* W_val  = (const float*)d_in[10];
  const float* b_val  = (const float*)d_in[11];
  const float* W_out  = (const float*)d_in[12];
  const float* b_out  = (const float*)d_in[13];

  float* ws = (float*)d_ws;
  float* v_val  = ws;                          // LQ*256
  float* v_attn = v_val + (size_t)LQ * 256;    // LQ*512
  float* v_off  = v_attn + (size_t)LQ * 512;   // LQ*1024
  float* v_ms   = v_off + (size_t)LQ * 1024;   // LQ*256
  float* outp = (float*)d_out;

  dim3 block(256);
  const int gm = (LQ + 63) / 64;  // 192

  gemm_bias_kernel<<<dim3(256 / 64, gm), block, 0, stream>>>(
      inflat, W_val, b_val, v_val, LQ, 256, 256);
  gemm_bias_kernel<<<dim3(512 / 64, gm), block, 0, stream>>>(
      query, W_attn, b_attn, v_attn, LQ, 512, 256);
  gemm_bias_kernel<<<dim3(1024 / 64, gm), block, 0, stream>>>(
      query, W_off, b_off, v_off, LQ, 1024, 256);
  sample_kernel<<<dim3(LQ / 2), block, 0, stream>>>(
      v_val, v_attn, v_off, tempoff, refpts, v_ms);
  gemm_bias_kernel<<<dim3(256 / 64, gm), block, 0, stream>>>(
      v_ms, W_out, b_out, outp, LQ, 256, 256);
}

// Round 4
// 179.445 us; speedup vs baseline: 2.2379x; 2.0495x over previous
//
#include <hip/hip_runtime.h>
#include <hip/hip_bf16.h>
#include <hip/hip_fp16.h>

#define LQ     12240
#define HEADS  8

typedef _Float16 half8 __attribute__((ext_vector_type(8)));
typedef float floatx4 __attribute__((ext_vector_type(4)));

// ---------------------------------------------------------------------------
// f32 -> f16 elementwise (float4 granularity)
// ---------------------------------------------------------------------------
__global__ __launch_bounds__(256) void cvt_f32_f16(
    const float* __restrict__ in, __half* __restrict__ out, int n4) {
  const int i = blockIdx.x * 256 + threadIdx.x;
  if (i >= n4) return;
  const float4 v = reinterpret_cast<const float4*>(in)[i];
  const __half2 a = __floats2half2_rn(v.x, v.y);
  const __half2 b = __floats2half2_rn(v.z, v.w);
  uint2 pk;
  pk.x = *reinterpret_cast<const unsigned int*>(&a);
  pk.y = *reinterpret_cast<const unsigned int*>(&b);
  reinterpret_cast<uint2*>(out)[i] = pk;
}

// ---------------------------------------------------------------------------
// Weight transpose + cvt: in f32 [256][N] -> out f16 [N][256]
// ---------------------------------------------------------------------------
__global__ __launch_bounds__(256) void transpose_cvt(
    const float* __restrict__ in, __half* __restrict__ out, int N) {
  __shared__ float t[32][33];
  const int n0 = blockIdx.x * 32, k0 = blockIdx.y * 32;
  const int c = threadIdx.x & 31, r = threadIdx.x >> 5;
#pragma unroll
  for (int i = 0; i < 4; ++i)
    t[r + i * 8][c] = in[(size_t)(k0 + r + i * 8) * N + n0 + c];
  __syncthreads();
#pragma unroll
  for (int i = 0; i < 4; ++i)
    out[(size_t)(n0 + r + i * 8) * 256 + k0 + c] = __float2half(t[c][r + i * 8]);
}

// ---------------------------------------------------------------------------
// f16 MFMA GEMM: C[M,N] = A[M,256] @ Bt[N,256]^T + bias[N]
// 128x128 tile, 4 waves (2x2), each wave 64x64 = 4x4 frags of 16x16x32.
// LDS granules (16B = 8 halves) XOR-swizzled: slot = g ^ (row & 7).
// ---------------------------------------------------------------------------
template <typename TC>
__device__ inline void store_c(TC* C, size_t idx, float v);
template <> __device__ inline void store_c<float>(float* C, size_t idx, float v) { C[idx] = v; }
template <> __device__ inline void store_c<__half>(__half* C, size_t idx, float v) { C[idx] = __float2half(v); }

template <typename TC>
__global__ __launch_bounds__(256) void gemm_mfma(
    const __half* __restrict__ A,    // [M][256]
    const __half* __restrict__ Bt,   // [N][256]
    const float* __restrict__ bias,  // [N]
    TC* __restrict__ C, int M, int N) {
  __shared__ uint4 As_g[128 * 8];
  __shared__ uint4 Bs_g[128 * 8];

  const int tid = threadIdx.x;
  const int bm = blockIdx.y * 128, bn = blockIdx.x * 128;
  const int wid = tid >> 6, lane = tid & 63;
  const int wr = wid >> 1, wn = wid & 1;
  const int l16 = lane & 15, lhi = lane >> 4;

  floatx4 acc[4][4] = {};

  const int srow = tid >> 1;        // 0..127
  const int sg0 = (tid & 1) * 4;    // 0 or 4
  const bool arow_ok = (bm + srow) < M;
  const __half* Arow = A + (size_t)(arow_ok ? bm + srow : 0) * 256;
  const __half* Brow = Bt + (size_t)(bn + srow) * 256;

  for (int ks = 0; ks < 4; ++ks) {
    const int k0 = ks * 64;
#pragma unroll
    for (int i = 0; i < 4; ++i) {
      const int g = sg0 + i;
      uint4 av = make_uint4(0, 0, 0, 0);
      if (arow_ok) av = *reinterpret_cast<const uint4*>(Arow + k0 + g * 8);
      As_g[srow * 8 + (g ^ (srow & 7))] = av;
      Bs_g[srow * 8 + (g ^ (srow & 7))] =
          *reinterpret_cast<const uint4*>(Brow + k0 + g * 8);
    }
    __syncthreads();

#pragma unroll
    for (int kk = 0; kk < 2; ++kk) {
      half8 a[4], b[4];
#pragma unroll
      for (int m = 0; m < 4; ++m) {
        const int row = wr * 64 + m * 16 + l16;
        const int g = kk * 4 + lhi;
        union { uint4 u; half8 h; } cv;
        cv.u = As_g[row * 8 + (g ^ (row & 7))];
        a[m] = cv.h;
      }
#pragma unroll
      for (int n = 0; n < 4; ++n) {
        const int row = wn * 64 + n * 16 + l16;
        const int g = kk * 4 + lhi;
        union { uint4 u; half8 h; } cv;
        cv.u = Bs_g[row * 8 + (g ^ (row & 7))];
        b[n] = cv.h;
      }
#pragma unroll
      for (int m = 0; m < 4; ++m)
#pragma unroll
        for (int n = 0; n < 4; ++n)
          acc[m][n] = __builtin_amdgcn_mfma_f32_16x16x32_f16(a[m], b[n], acc[m][n], 0, 0, 0);
    }
    __syncthreads();
  }

  // epilogue: D row = lhi*4 + r, col = l16 within each 16x16 frag
#pragma unroll
  for (int m = 0; m < 4; ++m) {
    const int row0 = bm + wr * 64 + m * 16 + lhi * 4;
#pragma unroll
    for (int n = 0; n < 4; ++n) {
      const int col = bn + wn * 64 + n * 16 + l16;
      const float bv = bias[col];
#pragma unroll
      for (int r = 0; r < 4; ++r) {
        const int row = row0 + r;
        if (row < M) store_c<TC>(C, (size_t)row * N + col, acc[m][n][r] + bv);
      }
    }
  }
}

// ---------------------------------------------------------------------------
// Fused softmax + location + deformable bilinear sampling, 2 queries / block.
// value/logits/off are f16; per-sample packed 16B LDS records, XOR-swizzled.
// ---------------------------------------------------------------------------
__global__ __launch_bounds__(256) void sample_kernel(
    const __half* __restrict__ value,     // (LQ, 256) f16
    const __half* __restrict__ logits,    // (LQ, 512) f16
    const __half* __restrict__ off,       // (LQ, 1024) f16
    const float* __restrict__ tempoff,    // (LQ, 4, 4, 2) f32
    const float* __restrict__ refpts,     // (LQ, 4, 2) f32
    __half* __restrict__ msout) {         // (LQ, 256) f16
  const int q0 = blockIdx.x * 2;
  const int tid = threadIdx.x;

  __shared__ float slog[1024];
  __shared__ uint4 sdat[1024];
  __shared__ float sm_m[16], sm_si[16];

#pragma unroll
  for (int k = 0; k < 4; ++k) {
    const int s = tid + k * 256;
    slog[s] = __half2float(logits[(size_t)(q0 + (s >> 9)) * 512 + (s & 511)]);
  }
  __syncthreads();

  {
    const int g = tid >> 4;
    const int j = tid & 15;
    const float* e = &slog[g * 64];
    float m = fmaxf(fmaxf(e[j], e[j + 16]), fmaxf(e[j + 32], e[j + 48]));
#pragma unroll
    for (int mask = 8; mask >= 1; mask >>= 1) m = fmaxf(m, __shfl_xor(m, mask));
    float s = __expf(e[j] - m) + __expf(e[j + 16] - m) +
              __expf(e[j + 32] - m) + __expf(e[j + 48] - m);
#pragma unroll
    for (int mask = 8; mask >= 1; mask >>= 1) s += __shfl_xor(s, mask);
    if (j == 0) { sm_m[g] = m; sm_si[g] = 1.0f / s; }
  }
  __syncthreads();

  const float HWF[4] = {2304.f, 576.f, 144.f, 36.f};
  const float RHW[4] = {1.f / 2304.f, 1.f / 576.f, 1.f / 144.f, 1.f / 36.f};
  const int   S0[4]  = {0, 9216, 11520, 12096};
  const int   HWI[4] = {2304, 576, 144, 36};

#pragma unroll
  for (int k = 0; k < 4; ++k) {
    const int s  = tid + k * 256;
    const int qi = s >> 9;
    const int i  = s & 511;
    const int h  = i >> 6;
    const int r  = i & 63;
    const int l  = r >> 4;
    const int f  = (r >> 2) & 3;
    const size_t q = (size_t)(q0 + qi);

    const float w = __expf(slog[s] - sm_m[s >> 6]) * sm_si[s >> 6];

    const float2 o  = __half22float2(*reinterpret_cast<const __half2*>(&off[q * 1024 + i * 2]));
    const float2 to = *reinterpret_cast<const float2*>(&tempoff[q * 32 + (l * 4 + f) * 2]);
    const float2 rp = *reinterpret_cast<const float2*>(&refpts[q * 8 + l * 2]);

    const float hw = HWF[l];
    const float x = (to.x + o.x * 0.25f + rp.x) * 4.0f - 0.5f;
    const float y = (to.y + o.y * RHW[l] + rp.y) * hw - 0.5f;

    const float x0f = floorf(x), y0f = floorf(y);
    const float fx = x - x0f, fy = y - y0f;
    const int x0 = (int)x0f, y0 = (int)y0f;
    const int hl = HWI[l];

    const bool xv0 = (x0 >= 0) && (x0 < 4);
    const bool xv1 = (x0 >= -1) && (x0 < 3);
    const bool yv0 = (y0 >= 0) && (y0 < hl);
    const bool yv1 = (y0 >= -1) && (y0 < hl - 1);
    const int xc0 = min(max(x0, 0), 3);
    const int xc1 = min(max(x0 + 1, 0), 3);
    const int yc0 = min(max(y0, 0), hl - 1);
    const int yc1 = min(max(y0 + 1, 0), hl - 1);

    const float w00 = (xv0 && yv0) ? w * (1.f - fx) * (1.f - fy) : 0.f;
    const float w01 = (xv1 && yv0) ? w * fx * (1.f - fy) : 0.f;
    const float w10 = (xv0 && yv1) ? w * (1.f - fx) * fy : 0.f;
    const float w11 = (xv1 && yv1) ? w * fx * fy : 0.f;

    const int base = S0[l];
    const unsigned int r00 = (unsigned int)(base + yc0 * 4 + xc0);
    const unsigned int r01 = (unsigned int)(base + yc0 * 4 + xc1);
    const unsigned int r10 = (unsigned int)(base + yc1 * 4 + xc0);
    const unsigned int r11 = (unsigned int)(base + yc1 * 4 + xc1);

    const __half2 p01 = __floats2half2_rn(w00, w01);
    const __half2 p23 = __floats2half2_rn(w10, w11);
    uint4 pk;
    pk.x = *reinterpret_cast<const unsigned int*>(&p01);
    pk.y = *reinterpret_cast<const unsigned int*>(&p23);
    pk.z = r00 | (r01 << 16);
    pk.w = r10 | (r11 << 16);

    sdat[(qi << 9) | (r << 3) | (h ^ (r & 7))] = pk;
  }
  __syncthreads();

  const int qi = tid >> 7;
  const int h  = (tid >> 4) & 7;
  const int d  = (tid & 15) * 2;

  const __half* __restrict__ vb = value + h * 32 + d;
  float2 acc = make_float2(0.f, 0.f);
  const int sbase = qi << 9;

#pragma unroll 4
  for (int k = 0; k < 64; ++k) {
    const uint4 pk = sdat[sbase | (k << 3) | (h ^ (k & 7))];
    const float2 w01 = __half22float2(*reinterpret_cast<const __half2*>(&pk.x));
    const float2 w23 = __half22float2(*reinterpret_cast<const __half2*>(&pk.y));
    const float2 v0 = __half22float2(*reinterpret_cast<const __half2*>(vb + ((pk.z & 0xffffu) << 8)));
    const float2 v1 = __half22float2(*reinterpret_cast<const __half2*>(vb + ((pk.z >> 16) << 8)));
    const float2 v2 = __half22float2(*reinterpret_cast<const __half2*>(vb + ((pk.w & 0xffffu) << 8)));
    const float2 v3 = __half22float2(*reinterpret_cast<const __half2*>(vb + ((pk.w >> 16) << 8)));
    acc.x = fmaf(w01.x, v0.x, acc.x);
    acc.y = fmaf(w01.x, v0.y, acc.y);
    acc.x = fmaf(w01.y, v1.x, acc.x);
    acc.y = fmaf(w01.y, v1.y, acc.y);
    acc.x = fmaf(w23.x, v2.x, acc.x);
    acc.y = fmaf(w23.x, v2.y, acc.y);
    acc.x = fmaf(w23.y, v3.x, acc.x);
    acc.y = fmaf(w23.y, v3.y, acc.y);
  }
  const __half2 hout = __floats2half2_rn(acc.x, acc.y);
  *reinterpret_cast<__half2*>(&msout[(size_t)(q0 + qi) * 256 + h * 32 + d]) = hout;
}

// ---------------------------------------------------------------------------
extern "C" void kernel_launch(void* const* d_in, const int* in_sizes, int n_in,
                              void* d_out, int out_size, void* d_ws, size_t ws_size,
                              hipStream_t stream) {
  const float* query   = (const float*)d_in[0];
  const float* refpts  = (const float*)d_in[1];
  const float* tempoff = (const float*)d_in[2];
  const float* inflat  = (const float*)d_in[3];
  const float* W_off  = (const float*)d_in[6];
  const float* b_off  = (const float*)d_in[7];
  const float* W_attn = (const float*)d_in[8];
  const float* b_attn = (const float*)d_in[9];
  const float* W_val  = (const float*)d_in[10];
  const float* b_val  = (const float*)d_in[11];
  const float* W_out  = (const float*)d_in[12];
  const float* b_out  = (const float*)d_in[13];

  char* ws = (char*)d_ws;
  const size_t szQ = (size_t)LQ * 256 * 2;  // 6,266,880
  __half* qh     = (__half*)ws;                 ws += szQ;
  __half* ifh    = (__half*)ws;                 ws += szQ;
  __half* wT_val = (__half*)ws;                 ws += (size_t)256 * 256 * 2;
  __half* wT_att = (__half*)ws;                 ws += (size_t)512 * 256 * 2;
  __half* wT_off = (__half*)ws;                 ws += (size_t)1024 * 256 * 2;
  __half* wT_out = (__half*)ws;                 ws += (size_t)256 * 256 * 2;
  __half* val_h  = (__half*)ws;                 ws += szQ;
  __half* attn_h = (__half*)ws;                 ws += (size_t)LQ * 512 * 2;
  __half* off_h  = (__half*)ws;                 ws += (size_t)LQ * 1024 * 2;
  __half* ms_h   = (__half*)ws;                 ws += szQ;

  const dim3 blk(256);
  const int n4 = LQ * 256 / 4;  // 783360 -> 3060 blocks

  cvt_f32_f16<<<dim3((n4 + 255) / 256), blk, 0, stream>>>(query, qh, n4);
  cvt_f32_f16<<<dim3((n4 + 255) / 256), blk, 0, stream>>>(inflat, ifh, n4);
  transpose_cvt<<<dim3(8, 8),  blk, 0, stream>>>(W_val,  wT_val, 256);
  transpose_cvt<<<dim3(16, 8), blk, 0, stream>>>(W_attn, wT_att, 512);
  transpose_cvt<<<dim3(32, 8), blk, 0, stream>>>(W_off,  wT_off, 1024);
  transpose_cvt<<<dim3(8, 8),  blk, 0, stream>>>(W_out,  wT_out, 256);

  const int gm = (LQ + 127) / 128;  // 96
  gemm_mfma<__half><<<dim3(2, gm), blk, 0, stream>>>(ifh, wT_val, b_val, val_h, LQ, 256);
  gemm_mfma<__half><<<dim3(4, gm), blk, 0, stream>>>(qh, wT_att, b_attn, attn_h, LQ, 512);
  gemm_mfma<__half><<<dim3(8, gm), blk, 0, stream>>>(qh, wT_off, b_off, off_h, LQ, 1024);

  sample_kernel<<<dim3(LQ / 2), blk, 0, stream>>>(val_h, attn_h, off_h, tempoff, refpts, ms_h);

  gemm_mfma<float><<<dim3(2, gm), blk, 0, stream>>>(ms_h, wT_out, b_out, (float*)d_out, LQ, 256);
}